// Round 8
// baseline (311.085 us; speedup 1.0000x reference)
//
#include <hip/hip_runtime.h>

#define EPSF 1e-5f
#define DECAYF 0.99f
#define KCODES 2048
#define DIM 256
#define CC 128         // 16 code-tiles x 8 d-chunks of 32
#define BUFSZ 32768
#define OFF_AH 0
#define OFF_AL 8192
#define OFF_BH 16384
#define OFF_BL 24576

typedef _Float16 f16;
typedef f16 f16x8 __attribute__((ext_vector_type(8)));
typedef float f32x4 __attribute__((ext_vector_type(4)));

#define MFMA16(A, B, C) __builtin_amdgcn_mfma_f32_16x16x32_f16(A, B, C, 0, 0, 0)

__device__ __forceinline__ void gload_lds16(const void* g, void* l) {
    __builtin_amdgcn_global_load_lds(
        (const __attribute__((address_space(1))) void*)g,
        (__attribute__((address_space(3))) void*)l, 16, 0, 0);
}

// ---------------------------------------------------------------------------
// fused split_x + prep_embed (independent jobs, one dispatch)
// blocks [0, NSPLIT): xh=(f16)x, xl=(f16)(x-xh), 8 elems/thread
// blocks [NSPLIT, NSPLIT+K): embed=embed_sum/clamp(usage), e2, eh/el split
// ---------------------------------------------------------------------------
__global__ __launch_bounds__(256) void split_prep_kernel(
    const float* __restrict__ x, f16* __restrict__ xh, f16* __restrict__ xl, int nsplit,
    const float* __restrict__ embed_sum, const float* __restrict__ usage,
    float* __restrict__ embed, f16* __restrict__ eh, f16* __restrict__ el,
    float* __restrict__ e2)
{
    if ((int)blockIdx.x < nsplit) {
        int i = blockIdx.x * 256 + threadIdx.x;
        f32x4 v0 = ((const f32x4*)x)[2 * i];
        f32x4 v1 = ((const f32x4*)x)[2 * i + 1];
        f16x8 h, l;
        #pragma unroll
        for (int t = 0; t < 4; ++t) {
            f16 h0 = (f16)v0[t]; h[t] = h0; l[t] = (f16)(v0[t] - (float)h0);
            f16 h1 = (f16)v1[t]; h[t + 4] = h1; l[t + 4] = (f16)(v1[t] - (float)h1);
        }
        ((f16x8*)xh)[i] = h;
        ((f16x8*)xl)[i] = l;
    } else {
        int k = blockIdx.x - nsplit;
        int d = threadIdx.x;
        float inv = 1.0f / fmaxf(usage[k], EPSF);
        float e = embed_sum[k * DIM + d] * inv;
        embed[k * DIM + d] = e;
        float ec = fminf(fmaxf(e, -65000.0f), 65000.0f);
        f16 h = (f16)ec;
        f16 l = (f16)(ec - (float)h);
        eh[k * DIM + d] = h;
        el[k * DIM + d] = l;
        float sq = e * e;
        #pragma unroll
        for (int off = 32; off > 0; off >>= 1) sq += __shfl_down(sq, off, 64);
        __shared__ float ws[4];
        if ((threadIdx.x & 63) == 0) ws[threadIdx.x >> 6] = sq;
        __syncthreads();
        if (threadIdx.x == 0) e2[k] = ws[0] + ws[1] + ws[2] + ws[3];
    }
}

// ---------------------------------------------------------------------------
// argmin: fragment-shared f16 GEMM-argmin, 2 blocks/CU for cross-block overlap.
// BM=BN=128, 8 waves (4M x 2N, wave tile 32x64), 16x16x32 f16.
// LDS 72KB (2 x 32KB dbuf + 8KB e2) -> 2 independent blocks/CU; their
// barrier phases drift so one block's ds_read burst hides under the other's
// MFMA (m114 overlap). Single s_barrier per 32-d chunk; XOR-swizzled LDS.
// __launch_bounds__(512,4) caps VGPR at 128 so 16 waves/CU fit.
// ---------------------------------------------------------------------------
__global__ __launch_bounds__(512, 4) void argmin_kernel(
    const f16* __restrict__ xh, const f16* __restrict__ xl,
    const f16* __restrict__ eh, const f16* __restrict__ el,
    const float* __restrict__ e2, int* __restrict__ flat_ind, int* __restrict__ cnt)
{
    __shared__ __align__(1024) char lds[2 * BUFSZ + 8192];
    float* e2s = (float*)(lds + 2 * BUFSZ);

    const int tid  = threadIdx.x;
    const int w    = tid >> 6, lane = tid & 63;
    const int l15  = lane & 15, l4 = lane >> 4;
    const int wm   = w >> 1, wn = w & 1;
    const int row0 = blockIdx.x * 128;
    const int gsw  = (lane & 3) ^ ((lane >> 3) & 3);     // write-side inverse swizzle
    const int lq   = lane >> 2;
    const int rslot = (l4 ^ ((l15 >> 1) & 3)) * 16;      // read-side swizzled slot

    f32x4 acc[2][4];
    float best[8];
    int   bidx[8];
    #pragma unroll
    for (int t = 0; t < 8; ++t) { best[t] = 3.4e38f; bidx[t] = 0; }

    auto stageU = [&](const f16* rowbase, int koff, char* unit) {
        const int r = w * 16 + lq;
        gload_lds16(rowbase + (size_t)r * DIM + koff + gsw * 8, unit + w * 1024);
    };

    // ---- prologue: e2 stash (lgkm-drained before first barrier), chunk 0 units
    ((f32x4*)e2s)[tid] = ((const f32x4*)e2)[tid];
    asm volatile("s_waitcnt lgkmcnt(0)" ::: "memory");
    stageU(xh + (size_t)row0 * DIM, 0, lds + OFF_AH);
    stageU(xl + (size_t)row0 * DIM, 0, lds + OFF_AL);
    stageU(eh, 0, lds + OFF_BH);
    stageU(el, 0, lds + OFF_BL);

    for (int cc = 0; cc < CC; ++cc) {
        char* buf  = lds + (cc & 1) * BUFSZ;
        char* nbuf = lds + ((cc + 1) & 1) * BUFSZ;
        const int ct = cc >> 3, sd = cc & 7;
        const int nn = cc + 1;
        const int nct = nn >> 3, nsd = nn & 7;
        const bool more = (nn < CC);

        if (sd == 0) {
            #pragma unroll
            for (int i = 0; i < 2; ++i)
                #pragma unroll
                for (int j = 0; j < 4; ++j)
                    acc[i][j] = (f32x4){0.f, 0.f, 0.f, 0.f};
        }

        // previous chunk's 4 staging loads (filling buf) complete: own-wave via
        // vmcnt(0) (issued a full chunk ago -> free), cross-wave via barrier.
        asm volatile("s_waitcnt vmcnt(0)" ::: "memory");
        __builtin_amdgcn_s_barrier();
        __builtin_amdgcn_sched_barrier(0);

        // issue next chunk's staging early; HBM latency hides under this chunk
        if (more) {
            stageU(xh + (size_t)row0 * DIM, nsd * 32, nbuf + OFF_AH);
            stageU(xl + (size_t)row0 * DIM, nsd * 32, nbuf + OFF_AL);
            stageU(eh + (size_t)(nct * 128) * DIM, nsd * 32, nbuf + OFF_BH);
            stageU(el + (size_t)(nct * 128) * DIM, nsd * 32, nbuf + OFF_BL);
        }

        // one region: 12 ds_read_b128 + 24 MFMA, compiler-interleaved
        f16x8 ah[2], al[2], bh[4], bl[4];
        #pragma unroll
        for (int i = 0; i < 2; ++i)
            ah[i] = *(const f16x8*)(buf + OFF_AH + (wm * 32 + i * 16 + l15) * 64 + rslot);
        #pragma unroll
        for (int j = 0; j < 4; ++j)
            bh[j] = *(const f16x8*)(buf + OFF_BH + (wn * 64 + j * 16 + l15) * 64 + rslot);
        #pragma unroll
        for (int i = 0; i < 2; ++i)
            #pragma unroll
            for (int j = 0; j < 4; ++j)
                acc[i][j] = MFMA16(ah[i], bh[j], acc[i][j]);
        #pragma unroll
        for (int i = 0; i < 2; ++i)
            al[i] = *(const f16x8*)(buf + OFF_AL + (wm * 32 + i * 16 + l15) * 64 + rslot);
        #pragma unroll
        for (int i = 0; i < 2; ++i)
            #pragma unroll
            for (int j = 0; j < 4; ++j)
                acc[i][j] = MFMA16(al[i], bh[j], acc[i][j]);
        #pragma unroll
        for (int j = 0; j < 4; ++j)
            bl[j] = *(const f16x8*)(buf + OFF_BL + (wn * 64 + j * 16 + l15) * 64 + rslot);
        #pragma unroll
        for (int i = 0; i < 2; ++i)
            #pragma unroll
            for (int j = 0; j < 4; ++j)
                acc[i][j] = MFMA16(ah[i], bl[j], acc[i][j]);

        // fold argmin at end of each 128-code tile
        if (sd == 7) {
            const int cbase = ct * 128 + wn * 64;
            #pragma unroll
            for (int j = 0; j < 4; ++j) {
                const int col = cbase + j * 16 + l15;
                const float e2v = e2s[col];
                #pragma unroll
                for (int i = 0; i < 2; ++i)
                    #pragma unroll
                    for (int r = 0; r < 4; ++r) {
                        float m = fmaf(-2.0f, acc[i][j][r], e2v);
                        const int t = i * 4 + r;
                        if (m < best[t]) { best[t] = m; bidx[t] = col; }
                    }
            }
        }
    }

    // ---- final reduce: 16 col-lanes, then 2 col-waves via LDS
    __syncthreads();
    float* rv = (float*)lds;            // [128][2]
    int*   ri = (int*)(lds + 1024);
    #pragma unroll
    for (int t = 0; t < 8; ++t) {
        float v = best[t];
        int  ix = bidx[t];
        #pragma unroll
        for (int m = 1; m <= 8; m <<= 1) {
            float ov = __shfl_xor(v, m, 64);
            int  oix = __shfl_xor(ix, m, 64);
            if (ov < v || (ov == v && oix < ix)) { v = ov; ix = oix; }
        }
        if (l15 == 0) {
            const int rl = wm * 32 + (t >> 2) * 16 + l4 * 4 + (t & 3);
            rv[rl * 2 + wn] = v;
            ri[rl * 2 + wn] = ix;
        }
    }
    __syncthreads();
    if (tid < 128) {
        float v0 = rv[tid * 2], v1 = rv[tid * 2 + 1];
        int   i0 = ri[tid * 2], i1 = ri[tid * 2 + 1];
        int ib = (v1 < v0 || (v1 == v0 && i1 < i0)) ? i1 : i0;
        flat_ind[row0 + tid] = ib;
        // wave-aggregated histogram (skew-proof)
        unsigned long long pending = ~0ULL;
        while (pending) {
            int leader = __ffsll((long long)pending) - 1;
            int lind = __shfl(ib, leader, 64);
            unsigned long long same = __ballot(ib == lind);
            if ((tid & 63) == leader) atomicAdd(&cnt[lind], (int)__popcll(same));
            pending &= ~same;
        }
    }
}

// ---------------------------------------------------------------------------
// scan: exclusive prefix sum over 2048 counts -> offsets, cursor
// ---------------------------------------------------------------------------
__global__ __launch_bounds__(256) void scan_kernel(
    const int* __restrict__ cnt, int* __restrict__ offs, int* __restrict__ cursor)
{
    __shared__ int ps[256];
    const int t = threadIdx.x;
    int pre[8], s = 0;
    #pragma unroll
    for (int j = 0; j < 8; ++j) { pre[j] = s; s += cnt[t * 8 + j]; }
    ps[t] = s;
    __syncthreads();
    for (int off = 1; off < 256; off <<= 1) {
        int v = (t >= off) ? ps[t - off] : 0;
        __syncthreads();
        ps[t] += v;
        __syncthreads();
    }
    int ex = (t > 0) ? ps[t - 1] : 0;
    #pragma unroll
    for (int j = 0; j < 8; ++j) {
        offs[t * 8 + j]   = ex + pre[j];
        cursor[t * 8 + j] = ex + pre[j];
    }
}

// ---------------------------------------------------------------------------
// assign: counting-sort placement with wave-aggregated cursor atomics.
// ---------------------------------------------------------------------------
__global__ __launch_bounds__(256) void assign_kernel(
    const int* __restrict__ flat_ind, int* __restrict__ cursor,
    int* __restrict__ rowlist, int* __restrict__ codesorted)
{
    const int i    = blockIdx.x * 256 + threadIdx.x;
    const int lane = threadIdx.x & 63;
    const int ind  = flat_ind[i];
    int pos = 0;
    unsigned long long pending = ~0ULL;
    while (pending) {
        int leader = __ffsll((long long)pending) - 1;
        int lind = __shfl(ind, leader, 64);
        unsigned long long same = __ballot(ind == lind);
        if (ind == lind) {
            int base = 0;
            if (lane == leader) base = atomicAdd(&cursor[lind], (int)__popcll(same));
            base = __shfl(base, leader, 64);
            pos = base + (int)__popcll(same & ((1ULL << lane) - 1ULL));
        }
        pending &= ~same;
    }
    rowlist[pos] = i;
    codesorted[pos] = ind;
}

// ---------------------------------------------------------------------------
// codesum: chunked segmented reduction over the sorted rowlist (skew-proof).
// ---------------------------------------------------------------------------
__global__ __launch_bounds__(256) void codesum_kernel(
    const float* __restrict__ x, const int* __restrict__ rowlist,
    const int* __restrict__ codesorted, float* __restrict__ sums)
{
    const int p0 = blockIdx.x * 64;
    __shared__ int rows[64], codes[64];
    if (threadIdx.x < 64) {
        rows[threadIdx.x]  = rowlist[p0 + threadIdx.x];
        codes[threadIdx.x] = codesorted[p0 + threadIdx.x];
    }
    __syncthreads();
    const int d = threadIdx.x;
    float acc = 0.f;
    int cur = codes[0];
    #pragma unroll 4
    for (int r = 0; r < 64; ++r) {
        const int c = codes[r];
        if (c != cur) {
            atomicAdd(&sums[(size_t)cur * DIM + d], acc);
            acc = 0.f; cur = c;
        }
        acc += x[(size_t)rows[r] * DIM + d];
    }
    atomicAdd(&sums[(size_t)cur * DIM + d], acc);
}

// ---------------------------------------------------------------------------
// fused quantize + finalize (both depend only on earlier kernels)
// blocks [0, NQ): out_q = embed[flat_ind], out_ind = (float)flat_ind
// blocks [NQ, NQ+K): EMA outputs from sums/cnt
// ---------------------------------------------------------------------------
__global__ __launch_bounds__(256) void quant_final_kernel(
    const float* __restrict__ embed, const int* __restrict__ flat_ind,
    float* __restrict__ out_q, float* __restrict__ out_ind_f, int N, int nq,
    const float* __restrict__ embed_sum, const float* __restrict__ usage,
    const float* __restrict__ sums, const int* __restrict__ cnt,
    float* __restrict__ out_usage, float* __restrict__ out_es)
{
    if ((int)blockIdx.x < nq) {
        int i = blockIdx.x * 256 + threadIdx.x;   // over N*64 float4s
        int row = i >> 6, c4 = i & 63;
        int ind = flat_ind[row];
        ((f32x4*)out_q)[i] = ((const f32x4*)embed)[ind * 64 + c4];
        if (i < N) out_ind_f[i] = (float)flat_ind[i];
    } else {
        const int k = blockIdx.x - nq, d = threadIdx.x;
        out_es[k * DIM + d] = embed_sum[k * DIM + d] * DECAYF + sums[k * DIM + d] * (1.0f - DECAYF);
        if (d == 0)
            out_usage[k] = usage[k] * DECAYF + (float)cnt[k] * (1.0f - DECAYF);
    }
}

extern "C" void kernel_launch(void* const* d_in, const int* in_sizes, int n_in,
                              void* d_out, int out_size, void* d_ws, size_t ws_size,
                              hipStream_t stream)
{
    const float* hs        = (const float*)d_in[0];
    const float* embed_sum = (const float*)d_in[1];
    const float* usage     = (const float*)d_in[2];
    const int N = in_sizes[0] / DIM;   // 65536

    float* ws_f      = (float*)d_ws;
    float* embed     = ws_f;                         // K*D f32
    float* e2        = embed + KCODES * DIM;         // K
    float* sums      = e2 + KCODES;                  // K*D f32  (memset w/ cnt)
    int*   cnt       = (int*)(sums + KCODES * DIM);  // K        (adjacent!)
    f16*   eh        = (f16*)(cnt + KCODES);         // K*D f16
    f16*   el        = eh + KCODES * DIM;            // K*D f16
    int*   offs      = (int*)(el + KCODES * DIM);    // K
    int*   cursor    = offs + KCODES;                // K
    int*   rowlist   = cursor + KCODES;              // N
    int*   codesorted= rowlist + N;                  // N
    int*   flat_ind  = codesorted + N;               // N

    float* out_q     = (float*)d_out;                // N*D
    float* out_ind   = out_q + (size_t)N * DIM;      // N
    float* out_usage = out_ind + N;                  // K
    float* out_es    = out_usage + KCODES;           // K*D

    // xh/xl live in the out_q region (exactly N*D*4B); quantize overwrites later
    f16* xh = (f16*)out_q;
    f16* xl = xh + (size_t)N * DIM;

    hipMemsetAsync(sums, 0, (size_t)(KCODES * DIM + KCODES) * sizeof(float), stream);

    const int nsplit = N * DIM / 8 / 256;            // 8192
    split_prep_kernel<<<nsplit + KCODES, 256, 0, stream>>>(
        hs, xh, xl, nsplit, embed_sum, usage, embed, eh, el, e2);
    argmin_kernel<<<N / 128, 512, 0, stream>>>(xh, xl, eh, el, e2, flat_ind, cnt);
    scan_kernel<<<1, 256, 0, stream>>>(cnt, offs, cursor);
    assign_kernel<<<N / 256, 256, 0, stream>>>(flat_ind, cursor, rowlist, codesorted);
    codesum_kernel<<<N / 64, 256, 0, stream>>>(hs, rowlist, codesorted, sums);
    const int nq = N * DIM / 4 / 256;                // 16384
    quant_final_kernel<<<nq + KCODES, 256, 0, stream>>>(
        embed, flat_ind, out_q, out_ind, N, nq,
        embed_sum, usage, sums, cnt, out_usage, out_es);
}